// Round 7
// baseline (634.918 us; speedup 1.0000x reference)
//
#include <hip/hip_runtime.h>
#include <hip/hip_bf16.h>
#include <stdint.h>

// Problem constants (B,H,S,D) = (2,16,2048,64); softmax is over the HEAD axis.
#define B_ 2
#define H_ 16
#define S_ 2048
#define D_ 64

typedef __attribute__((ext_vector_type(8))) short bf16x8;
typedef __attribute__((ext_vector_type(4))) float f32x4;
typedef __attribute__((ext_vector_type(4))) unsigned short u16x4;

__device__ __forceinline__ short f2bf(float x){
  union { float f; uint32_t u; } v; v.f = x;
  uint32_t r = v.u + 0x7FFFu + ((v.u >> 16) & 1u);   // round-to-nearest-even
  return (short)(r >> 16);
}
__device__ __forceinline__ float bf2f(short s){
  union { uint32_t u; float f; } v; v.u = ((uint32_t)(uint16_t)s) << 16;
  return v.f;
}

// LDS-only barrier: order LDS ops across waves WITHOUT draining vmem stores.
// (__syncthreads would emit s_waitcnt vmcnt(0) and serialize the p-store drain.)
#define LDS_BARRIER() do {                                  \
  __builtin_amdgcn_sched_barrier(0);                        \
  asm volatile("s_waitcnt lgkmcnt(0)" ::: "memory");        \
  __builtin_amdgcn_s_barrier();                             \
  __builtin_amdgcn_sched_barrier(0);                        \
} while (0)

// ---------- prep 1: K -> bf16 hi/lo split ----------
__global__ __launch_bounds__(256) void cast_k(const float* __restrict__ K,
                                              short* __restrict__ Khi,
                                              short* __restrict__ Klo){
  size_t idx = ((size_t)blockIdx.x * 256 + threadIdx.x) * 8;
  float4 a = *(const float4*)(K + idx);
  float4 b = *(const float4*)(K + idx + 4);
  float v[8] = {a.x,a.y,a.z,a.w,b.x,b.y,b.z,b.w};
  bf16x8 vh, vl;
  #pragma unroll
  for (int i = 0; i < 8; ++i){
    short hi = f2bf(v[i]);
    vh[i] = hi;
    vl[i] = f2bf(v[i] - bf2f(hi));
  }
  *(bf16x8*)(Khi + idx) = vh;
  *(bf16x8*)(Klo + idx) = vl;
}

// ---------- prep 2: V -> Vt[b,h,d,k] bf16 (transposed) ----------
__global__ __launch_bounds__(256) void transpose_v(const float* __restrict__ V,
                                                   short* __restrict__ Vt){
  __shared__ float T[64][65];
  int bh = blockIdx.x >> 5;          // 0..31  (B*H)
  int k0 = (blockIdx.x & 31) * 64;   // S/64 = 32 chunks
  int t = threadIdx.x;
  {
    int col = (t & 15) * 4;          // d
    #pragma unroll
    for (int i = 0; i < 4; ++i){
      int row = (t >> 4) + i * 16;   // k within chunk
      float4 a = *(const float4*)(V + ((size_t)bh * S_ + k0 + row) * D_ + col);
      T[col+0][row] = a.x; T[col+1][row] = a.y; T[col+2][row] = a.z; T[col+3][row] = a.w;
    }
  }
  __syncthreads();
  {
    int d  = t >> 2;
    int kk = (t & 3) * 16;
    bf16x8 o0, o1;
    #pragma unroll
    for (int j = 0; j < 8; ++j){
      o0[j] = f2bf(T[d][kk + j]);
      o1[j] = f2bf(T[d][kk + 8 + j]);
    }
    short* dst = Vt + ((size_t)bh * D_ + d) * S_ + k0 + kk;
    *(bf16x8*)(dst)     = o0;
    *(bf16x8*)(dst + 8) = o1;
  }
}

// ---------- main fused kernel ----------
// grid = B * S/16 = 256 blocks, 1024 threads (16 waves), wave <-> head.
// KBLK = 64. Barriers are LDS-only (no vmcnt drain); p-stores are fully
// line-coalesced (4 rows x 256B per instruction) and nontemporal; V-loads
// hoisted to phase A so their vmcnt waits never drain stores.
__global__ __launch_bounds__(1024, 4) void attn_main(
    const float* __restrict__ Q, const short* __restrict__ Khi,
    const short* __restrict__ Klo, const short* __restrict__ Vt,
    const int* __restrict__ mask, float* __restrict__ out,
    float* __restrict__ pout)
{
  __shared__ unsigned short sc[2][H_][1024];  // 64 KB (dbuf bf16 e, swizzled k)
  __shared__ float zb[2][1024];               // 8 KB (unswizzled: z[k] per q)
  __shared__ float cb[2][1024];               // 8 KB

  const int tid  = threadIdx.x;
  const int h    = tid >> 6;         // wave id == head
  const int lane = tid & 63;
  const int g    = lane >> 4;        // 0..3
  const int lr   = lane & 15;

  const int b  = blockIdx.x >> 7;          // 128 blocks per b
  const int q0 = (blockIdx.x & 127) << 4;  // 16 q-rows per block
  const int nIt = S_ / 64;                 // 32 k-tiles

  const size_t bh = (size_t)b * H_ + h;

  // Q fragments (A-operand): lane holds Q[q0+lr][c*32 + g*8 + i], hi/lo split
  bf16x8 qhi[2], qlo[2];
  {
    const float* qp = Q + (bh * S_ + q0 + lr) * D_ + g * 8;
    #pragma unroll
    for (int c = 0; c < 2; ++c){
      float4 a  = *(const float4*)(qp + c*32);
      float4 d4 = *(const float4*)(qp + c*32 + 4);
      float v[8] = {a.x,a.y,a.z,a.w,d4.x,d4.y,d4.z,d4.w};
      #pragma unroll
      for (int i = 0; i < 8; ++i){
        short hi = f2bf(v[i]);
        qhi[c][i] = hi;
        qlo[c][i] = f2bf(v[i] - bf2f(hi));
      }
    }
  }

  f32x4 o[4];
  #pragma unroll
  for (int j = 0; j < 4; ++j) o[j] = (f32x4){0.f,0.f,0.f,0.f};

  const int swzq = 4 * (lr & 7);     // fragment-path swizzle for q = lr

  const short* kbase_hi = Khi + (bh * S_ + lr) * D_ + g * 8;
  const short* kbase_lo = Klo + (bh * S_ + lr) * D_ + g * 8;
  const short* vbase    = Vt  + (bh * D_ + lr) * S_ + g * 8;
  // coalesced p-store base: lane (g,lr) -> row 4*step+g, 16B chunk lr
  float*       pstbase  = pout + (bh * S_ + q0 + g) * S_ + 4 * lr;

  // per-thread mask element for phase B: (q = tid>>6, k = tid&63)
  const int* mp = mask + ((size_t)b * S_ + q0 + (tid >> 6)) * S_ + (tid & 63);
  int mreg = mp[0];

  for (int it = 0; it < nIt; ++it){
    const int k0  = it * 64;
    const int buf = it & 1;

    // hoisted V fragments for phase C (issued before any stores this iter)
    bf16x8 vreg[4][2];
    #pragma unroll
    for (int j = 0; j < 4; ++j){
      #pragma unroll
      for (int m = 0; m < 2; ++m)
        vreg[j][m] = *(const bf16x8*)(vbase + (size_t)(16*j) * S_ + k0 + 32*m);
    }

    // prefetch next iteration's mask value (consumed after the next barrier)
    int mnext = 0;
    if (it + 1 < nIt) mnext = mp[(it + 1) * 64];

    // ---- phase A: scores for 4 16-k subtiles + exp -> LDS ----
    f32x4 s[4];
    #pragma unroll
    for (int t = 0; t < 4; ++t){
      s[t] = (f32x4){0.f,0.f,0.f,0.f};
      #pragma unroll
      for (int c = 0; c < 2; ++c){
        bf16x8 kh = *(const bf16x8*)(kbase_hi + (size_t)(k0 + 16*t) * D_ + c*32);
        bf16x8 kl = *(const bf16x8*)(kbase_lo + (size_t)(k0 + 16*t) * D_ + c*32);
        s[t] = __builtin_amdgcn_mfma_f32_16x16x32_bf16(qhi[c], kh, s[t], 0, 0, 0);
        s[t] = __builtin_amdgcn_mfma_f32_16x16x32_bf16(qlo[c], kh, s[t], 0, 0, 0);
        s[t] = __builtin_amdgcn_mfma_f32_16x16x32_bf16(qhi[c], kl, s[t], 0, 0, 0);
      }
    }
    #pragma unroll
    for (int t = 0; t < 4; ++t){
      #pragma unroll
      for (int r = 0; r < 4; ++r){
        int q = 4*g + r;             // C/D layout: row = 4*(lane>>4)+reg
        int k = 16*t + lr;           // col = lane&15 (+16 per subtile)
        float e = __expf(s[t][r] * 0.125f);
        sc[buf][h][q*64 + (k ^ (4*(q&7)))] = (unsigned short)f2bf(e);
      }
    }
    LDS_BARRIER();

    // ---- phase B: denom over heads -> z,c (all 1024 threads; unswizzled) ----
    {
      int q = tid >> 6, k = tid & 63;
      int ks = q*64 + (k ^ (4*(q&7)));
      float dsum = 0.f;
      #pragma unroll
      for (int hh = 0; hh < H_; ++hh) dsum += bf2f((short)sc[buf][hh][ks]);
      zb[buf][q*64 + k] = mreg ? (1.0f / dsum) : 0.0f;
      cb[buf][q*64 + k] = mreg ? 0.0f : 0.0625f;
    }
    LDS_BARRIER();

    // ---- phase C ----
    // C1: coalesced p_attn stores — lane (g,lr): row 4*st+g, 16B chunk lr.
    //     Each instruction: 4 rows x 256B contiguous = fully-covered 64B lines.
    {
      #pragma unroll
      for (int st = 0; st < 4; ++st){
        int q  = 4*st + g;
        int ke = 4*lr;                          // element k offset
        int ksw = (ke) ^ (4*(q&7));             // sc swizzle (4-aligned safe)
        u16x4 ev = *(const u16x4*)&sc[buf][h][q*64 + ksw];
        f32x4 zv = *(const f32x4*)&zb[buf][q*64 + ke];
        f32x4 cv = *(const f32x4*)&cb[buf][q*64 + ke];
        f32x4 pv;
        #pragma unroll
        for (int t2 = 0; t2 < 4; ++t2) pv[t2] = bf2f((short)ev[t2]) * zv[t2] + cv[t2];
        __builtin_nontemporal_store(pv, (f32x4*)(pstbase + (size_t)(4*st) * S_ + k0));
      }
    }
    // C2: fragment-path p -> pa, then PV MFMA with hoisted V regs
    {
      const unsigned short* sp = &sc[buf][h][lr*64];
      const float* zp = &zb[buf][lr*64];
      const float* cp = &cb[buf][lr*64];
      bf16x8 pa[2];
      #pragma unroll
      for (int m = 0; m < 2; ++m){
        int kb = 32*m + 8*g;
        int b1 = kb ^ swzq;             // swizzled e quad; z/c are unswizzled
        int b2 = b1 ^ 4;
        u16x4 eh0 = *(const u16x4*)(sp + b1);
        u16x4 eh1 = *(const u16x4*)(sp + b2);
        f32x4 z0 = *(const f32x4*)(zp + kb);
        f32x4 z1 = *(const f32x4*)(zp + kb + 4);
        f32x4 c0 = *(const f32x4*)(cp + kb);
        f32x4 c1 = *(const f32x4*)(cp + kb + 4);
        float p[8];
        #pragma unroll
        for (int j = 0; j < 4; ++j){
          p[j]     = bf2f((short)eh0[j]) * z0[j] + c0[j];
          p[4 + j] = bf2f((short)eh1[j]) * z1[j] + c1[j];
        }
        #pragma unroll
        for (int i = 0; i < 8; ++i) pa[m][i] = f2bf(p[i]);
      }
      #pragma unroll
      for (int j = 0; j < 4; ++j){
        o[j] = __builtin_amdgcn_mfma_f32_16x16x32_bf16(pa[0], vreg[j][0], o[j], 0, 0, 0);
        o[j] = __builtin_amdgcn_mfma_f32_16x16x32_bf16(pa[1], vreg[j][1], o[j], 0, 0, 0);
      }
    }
    mreg = mnext;
    // next iteration writes buf^1; the barrier pair orders LDS reuse
  }

  // ---- epilogue: out[b,h,q0+4g+r][16j+lr] ----
  #pragma unroll
  for (int j = 0; j < 4; ++j){
    #pragma unroll
    for (int r = 0; r < 4; ++r){
      out[(bh * S_ + q0 + 4*g + r) * D_ + 16*j + lr] = o[j][r];
    }
  }
}

extern "C" void kernel_launch(void* const* d_in, const int* in_sizes, int n_in,
                              void* d_out, int out_size, void* d_ws, size_t ws_size,
                              hipStream_t stream){
  const float* Q    = (const float*)d_in[0];
  const float* K    = (const float*)d_in[1];
  const float* V    = (const float*)d_in[2];
  const int*   mask = (const int*)d_in[3];

  const size_t nkv = (size_t)B_ * H_ * S_ * D_;   // 4,194,304

  short* Khi = (short*)d_ws;          // 8.4 MB
  short* Klo = Khi + nkv;             // 8.4 MB
  short* Vt  = Klo + nkv;             // 8.4 MB  (total 25.2 MB of ws)

  float* out  = (float*)d_out;        // [B,H,S,D]
  float* pout = out + nkv;            // [B,H,S,S]

  cast_k<<<(int)(nkv / (256 * 8)), 256, 0, stream>>>(K, Khi, Klo);
  transpose_v<<<B_ * H_ * (S_ / 64), 256, 0, stream>>>(V, Vt);
  attn_main<<<B_ * (S_ / 16), 1024, 0, stream>>>(Q, Khi, Klo, Vt, mask, out, pout);
}

// Round 8
// 603.648 us; speedup vs baseline: 1.0518x; 1.0518x over previous
//
#include <hip/hip_runtime.h>
#include <hip/hip_bf16.h>
#include <stdint.h>

// Problem constants (B,H,S,D) = (2,16,2048,64); softmax is over the HEAD axis.
#define B_ 2
#define H_ 16
#define S_ 2048
#define D_ 64

typedef __attribute__((ext_vector_type(8))) short bf16x8;
typedef __attribute__((ext_vector_type(4))) float f32x4;

__device__ __forceinline__ short f2bf(float x){
  union { float f; uint32_t u; } v; v.f = x;
  uint32_t r = v.u + 0x7FFFu + ((v.u >> 16) & 1u);   // round-to-nearest-even
  return (short)(r >> 16);
}

// ---------- prep 1: fp32 -> bf16 (K) ----------
__global__ __launch_bounds__(256) void cast_bf16(const float* __restrict__ X,
                                                 short* __restrict__ Y){
  size_t idx = ((size_t)blockIdx.x * 256 + threadIdx.x) * 8;
  float4 a = *(const float4*)(X + idx);
  float4 b = *(const float4*)(X + idx + 4);
  bf16x8 v;
  v[0]=f2bf(a.x); v[1]=f2bf(a.y); v[2]=f2bf(a.z); v[3]=f2bf(a.w);
  v[4]=f2bf(b.x); v[5]=f2bf(b.y); v[6]=f2bf(b.z); v[7]=f2bf(b.w);
  *(bf16x8*)(Y + idx) = v;
}

// ---------- prep 2: V -> Vt[b,h,d,k] bf16 (transposed) ----------
__global__ __launch_bounds__(256) void transpose_v(const float* __restrict__ V,
                                                   short* __restrict__ Vt){
  __shared__ float T[64][65];
  int bh = blockIdx.x >> 5;          // 0..31  (B*H)
  int k0 = (blockIdx.x & 31) * 64;   // S/64 = 32 chunks
  int t = threadIdx.x;
  {
    int col = (t & 15) * 4;          // d
    #pragma unroll
    for (int i = 0; i < 4; ++i){
      int row = (t >> 4) + i * 16;   // k within chunk
      float4 a = *(const float4*)(V + ((size_t)bh * S_ + k0 + row) * D_ + col);
      T[col+0][row] = a.x; T[col+1][row] = a.y; T[col+2][row] = a.z; T[col+3][row] = a.w;
    }
  }
  __syncthreads();
  {
    int d  = t >> 2;
    int kk = (t & 3) * 16;
    bf16x8 o0, o1;
    #pragma unroll
    for (int j = 0; j < 8; ++j){
      o0[j] = f2bf(T[d][kk + j]);
      o1[j] = f2bf(T[d][kk + 8 + j]);
    }
    short* dst = Vt + ((size_t)bh * D_ + d) * S_ + k0 + kk;
    *(bf16x8*)(dst)     = o0;
    *(bf16x8*)(dst + 8) = o1;
  }
}

// ---------- pass 1: Z[b,q,k] = masked ? -1 : 1/sum_h exp(s_h/8) ----------
// 512 blocks x 256 thr; wave = (b, k-strip of 256, q-tile of 16); waves in a
// block share (b,strip) -> K strip L1/L2-shared. No LDS, no barriers.
__global__ __launch_bounds__(256) void pass1(const float* __restrict__ Q,
                                             const short* __restrict__ Khi,
                                             const int* __restrict__ mask,
                                             float* __restrict__ Z){
  const int tid = threadIdx.x, w = tid >> 6, lane = tid & 63;
  const int g = lane >> 4, lr = lane & 15;
  const int bid = blockIdx.x;
  const int qg = bid >> 4, b = (bid >> 3) & 1, strip = bid & 7;
  const int q0 = (qg * 4 + w) * 16;
  const int ks0 = strip * 256;

  // Q fragments: 16 heads x 2 c-halves, single bf16
  bf16x8 qh[16][2];
  #pragma unroll
  for (int h = 0; h < 16; ++h){
    const float* qp = Q + (((size_t)(b*16 + h)) * S_ + q0 + lr) * D_ + g * 8;
    #pragma unroll
    for (int c = 0; c < 2; ++c){
      float4 a  = *(const float4*)(qp + c*32);
      float4 d4 = *(const float4*)(qp + c*32 + 4);
      bf16x8 v;
      v[0]=f2bf(a.x); v[1]=f2bf(a.y); v[2]=f2bf(a.z); v[3]=f2bf(a.w);
      v[4]=f2bf(d4.x); v[5]=f2bf(d4.y); v[6]=f2bf(d4.z); v[7]=f2bf(d4.w);
      qh[h][c] = v;
    }
  }

  for (int st = 0; st < 16; ++st){
    const int kk = ks0 + st * 16;
    f32x4 dsum = (f32x4){0.f,0.f,0.f,0.f};
    #pragma unroll 4
    for (int h = 0; h < 16; ++h){
      f32x4 s = (f32x4){0.f,0.f,0.f,0.f};
      #pragma unroll
      for (int c = 0; c < 2; ++c){
        bf16x8 kh = *(const bf16x8*)(Khi + (((size_t)(b*16 + h)) * S_ + kk + lr) * D_ + c*32 + g*8);
        s = __builtin_amdgcn_mfma_f32_16x16x32_bf16(qh[h][c], kh, s, 0, 0, 0);
      }
      #pragma unroll
      for (int r = 0; r < 4; ++r) dsum[r] += __expf(s[r] * 0.125f);
    }
    #pragma unroll
    for (int r = 0; r < 4; ++r){
      const size_t qrow = (size_t)b * S_ + q0 + 4*g + r;
      int m = mask[qrow * S_ + kk + lr];
      Z[qrow * S_ + kk + lr] = m ? (1.0f / dsum[r]) : -1.0f;
    }
  }
}

// ---------- pass 2: p = z<0 ? 1/16 : exp(s/8)*z ; store p ; out = P V ----------
// 256 blocks x 1024 thr (16 waves); wave = (b,h,q16), block = (b,h,q-strip256).
// NO barriers: waves free-run; P transposed via wave-private swizzled LDS.
// XCD decode: h in low bits -> each XCD hosts 4 (b,h) pairs; K+V L2-resident.
__global__ __launch_bounds__(1024) void pass2(const float* __restrict__ Q,
                                              const short* __restrict__ Khi,
                                              const short* __restrict__ Vt,
                                              const float* __restrict__ Z,
                                              float* __restrict__ out,
                                              float* __restrict__ pout){
  __shared__ short pl[16][16][64];   // 32 KB: [wave][q][k-swizzled]

  const int tid = threadIdx.x, w = tid >> 6, lane = tid & 63;
  const int g = lane >> 4, lr = lane & 15;
  const int bid = blockIdx.x;
  const int strip = (bid >> 5) & 7, b = (bid >> 4) & 1, h = bid & 15;
  const int q0 = strip * 256 + w * 16;
  const size_t bh = (size_t)b * 16 + h;

  // Q fragment (single bf16)
  bf16x8 qf[2];
  {
    const float* qp = Q + (bh * S_ + q0 + lr) * D_ + g * 8;
    #pragma unroll
    for (int c = 0; c < 2; ++c){
      float4 a  = *(const float4*)(qp + c*32);
      float4 d4 = *(const float4*)(qp + c*32 + 4);
      bf16x8 v;
      v[0]=f2bf(a.x); v[1]=f2bf(a.y); v[2]=f2bf(a.z); v[3]=f2bf(a.w);
      v[4]=f2bf(d4.x); v[5]=f2bf(d4.y); v[6]=f2bf(d4.z); v[7]=f2bf(d4.w);
      qf[c] = v;
    }
  }

  f32x4 o[4];
  #pragma unroll
  for (int j = 0; j < 4; ++j) o[j] = (f32x4){0.f,0.f,0.f,0.f};

  const short* kb = Khi + (bh * S_ + lr) * D_ + g * 8;
  const short* vb = Vt  + (bh * D_ + lr) * S_ + g * 8;
  const float* zl = Z    + ((size_t)b * S_ + q0 + 4*g) * S_ + lr;
  float*       pp = pout + (bh * S_ + q0 + 4*g) * S_ + lr;
  short*       plw = &pl[w][0][0];
  const int rm = 8 * ((lr ^ (lr >> 3)) & 7);   // read-side row swizzle (q=lr)

  for (int it = 0; it < 32; ++it){
    const int k0 = it * 64;

    // z loads (independent; issue early)
    f32x4 zv[4];
    #pragma unroll
    for (int t = 0; t < 4; ++t)
      #pragma unroll
      for (int r = 0; r < 4; ++r)
        zv[t][r] = zl[(size_t)r * S_ + k0 + 16*t];

    // QK^T
    f32x4 s[4];
    #pragma unroll
    for (int t = 0; t < 4; ++t){
      s[t] = (f32x4){0.f,0.f,0.f,0.f};
      #pragma unroll
      for (int c = 0; c < 2; ++c){
        bf16x8 kh = *(const bf16x8*)(kb + (size_t)(k0 + 16*t) * D_ + c*32);
        s[t] = __builtin_amdgcn_mfma_f32_16x16x32_bf16(qf[c], kh, s[t], 0, 0, 0);
      }
    }

    // V fragments (issued before p-stores so their wait skips the stores)
    bf16x8 vr[4][2];
    #pragma unroll
    for (int j = 0; j < 4; ++j)
      #pragma unroll
      for (int m = 0; m < 2; ++m)
        vr[j][m] = *(const bf16x8*)(vb + (size_t)(16*j) * S_ + k0 + 32*m);

    // e, p, global p-store, LDS transpose-write (swizzled, conflict-free)
    #pragma unroll
    for (int t = 0; t < 4; ++t){
      #pragma unroll
      for (int r = 0; r < 4; ++r){
        float e = __expf(s[t][r] * 0.125f);
        float z = zv[t][r];
        float p = (z < 0.f) ? 0.0625f : e * z;
        pp[(size_t)r * S_ + k0 + 16*t] = p;
        int q = 4*g + r;
        int ksw = (16*t + lr) ^ (8 * ((q ^ (q >> 3)) & 7));
        plw[q*64 + ksw] = f2bf(p);
      }
    }

    // wave-private transpose read (compiler inserts lgkmcnt; no s_barrier)
    bf16x8 pa0 = *(const bf16x8*)(plw + lr*64 + (( 0 + 8*g) ^ rm));
    bf16x8 pa1 = *(const bf16x8*)(plw + lr*64 + ((32 + 8*g) ^ rm));

    #pragma unroll
    for (int j = 0; j < 4; ++j){
      o[j] = __builtin_amdgcn_mfma_f32_16x16x32_bf16(pa0, vr[j][0], o[j], 0, 0, 0);
      o[j] = __builtin_amdgcn_mfma_f32_16x16x32_bf16(pa1, vr[j][1], o[j], 0, 0, 0);
    }
  }

  // epilogue
  #pragma unroll
  for (int j = 0; j < 4; ++j)
    #pragma unroll
    for (int r = 0; r < 4; ++r)
      out[(bh * S_ + q0 + 4*g + r) * D_ + 16*j + lr] = o[j][r];
}

extern "C" void kernel_launch(void* const* d_in, const int* in_sizes, int n_in,
                              void* d_out, int out_size, void* d_ws, size_t ws_size,
                              hipStream_t stream){
  const float* Q    = (const float*)d_in[0];
  const float* K    = (const float*)d_in[1];
  const float* V    = (const float*)d_in[2];
  const int*   mask = (const int*)d_in[3];

  const size_t nkv = (size_t)B_ * H_ * S_ * D_;   // 4,194,304

  short* Khi = (short*)d_ws;                       // 8.4 MB
  short* Vt  = Khi + nkv;                          // 8.4 MB
  float* Zb  = (float*)(Vt + nkv);                 // 33.5 MB (B*S*S fp32)

  float* out  = (float*)d_out;        // [B,H,S,D]
  float* pout = out + nkv;            // [B,H,S,S]

  cast_bf16  <<<(int)(nkv / (256 * 8)), 256, 0, stream>>>(K, Khi);
  transpose_v<<<B_ * H_ * (S_ / 64),    256, 0, stream>>>(V, Vt);
  pass1      <<<512,                    256, 0, stream>>>(Q, Khi, mask, Zb);
  pass2      <<<256,                   1024, 0, stream>>>(Q, Khi, Vt, Zb, out, pout);
}

// Round 9
// 513.121 us; speedup vs baseline: 1.2374x; 1.1764x over previous
//
#include <hip/hip_runtime.h>
#include <hip/hip_bf16.h>
#include <stdint.h>

// Problem constants (B,H,S,D) = (2,16,2048,64); softmax is over the HEAD axis.
#define B_ 2
#define H_ 16
#define S_ 2048
#define D_ 64

typedef __attribute__((ext_vector_type(8))) short bf16x8;
typedef __attribute__((ext_vector_type(4))) float f32x4;

__device__ __forceinline__ short f2bf(float x){
  union { float f; uint32_t u; } v; v.f = x;
  uint32_t r = v.u + 0x7FFFu + ((v.u >> 16) & 1u);   // round-to-nearest-even
  return (short)(r >> 16);
}

// LDS transpose swizzle: w(q) = ((q>>2)<<1)|(q&1) — bits[2:1] bijective in
// g=q>>2 so the 8 write instances (4 g-rows x lr-half) hit 8 distinct 4-bank
// windows; read side stays uniform-coverage b128.
__device__ __forceinline__ int wfun(int x){ return (((x >> 2) << 1) | (x & 1)) & 7; }

// ---------- prep 1: fp32 -> bf16 ----------
__global__ __launch_bounds__(256) void cast_bf16(const float* __restrict__ X,
                                                 short* __restrict__ Y){
  size_t idx = ((size_t)blockIdx.x * 256 + threadIdx.x) * 8;
  float4 a = *(const float4*)(X + idx);
  float4 b = *(const float4*)(X + idx + 4);
  bf16x8 v;
  v[0]=f2bf(a.x); v[1]=f2bf(a.y); v[2]=f2bf(a.z); v[3]=f2bf(a.w);
  v[4]=f2bf(b.x); v[5]=f2bf(b.y); v[6]=f2bf(b.z); v[7]=f2bf(b.w);
  *(bf16x8*)(Y + idx) = v;
}

// ---------- prep 2: V -> Vt[b,h,d,k] bf16 (transposed) ----------
__global__ __launch_bounds__(256) void transpose_v(const float* __restrict__ V,
                                                   short* __restrict__ Vt){
  __shared__ float T[64][65];
  int bh = blockIdx.x >> 5;          // 0..31  (B*H)
  int k0 = (blockIdx.x & 31) * 64;   // S/64 = 32 chunks
  int t = threadIdx.x;
  {
    int col = (t & 15) * 4;          // d
    #pragma unroll
    for (int i = 0; i < 4; ++i){
      int row = (t >> 4) + i * 16;   // k within chunk
      float4 a = *(const float4*)(V + ((size_t)bh * S_ + k0 + row) * D_ + col);
      T[col+0][row] = a.x; T[col+1][row] = a.y; T[col+2][row] = a.z; T[col+3][row] = a.w;
    }
  }
  __syncthreads();
  {
    int d  = t >> 2;
    int kk = (t & 3) * 16;
    bf16x8 o0, o1;
    #pragma unroll
    for (int j = 0; j < 8; ++j){
      o0[j] = f2bf(T[d][kk + j]);
      o1[j] = f2bf(T[d][kk + 8 + j]);
    }
    short* dst = Vt + ((size_t)bh * D_ + d) * S_ + k0 + kk;
    *(bf16x8*)(dst)     = o0;
    *(bf16x8*)(dst + 8) = o1;
  }
}

// ---------- pass 1: Z[b,q,k] = masked ? -1 : 1/sum_h exp(s_h/8) ----------
// 1024 blocks x 256 thr (4 waves). Block = (b, q64-group, k128-strip); wave =
// one q16 tile. h-OUTER loop: dsum[8][4] k-strip accumulator in 32 VGPRs,
// Q fragments loaded per-h (bf16, pre-cast) -> VGPR ~90, 4 waves/SIMD.
// No LDS, no barriers.
__global__ __launch_bounds__(256, 4) void pass1(const short* __restrict__ Qb,
                                                const short* __restrict__ Kb,
                                                const int* __restrict__ mask,
                                                float* __restrict__ Z){
  const int tid = threadIdx.x, w = tid >> 6, lane = tid & 63;
  const int g = lane >> 4, lr = lane & 15;
  const int bid = blockIdx.x;
  const int qg    = bid & 31;          // 32 q-groups of 64
  const int strip = (bid >> 5) & 15;   // 16 k-strips of 128
  const int b     = bid >> 9;
  const int q0 = qg * 64 + w * 16;
  const int ks = strip * 128;

  float dsum[8][4];
  #pragma unroll
  for (int st = 0; st < 8; ++st)
    #pragma unroll
    for (int r = 0; r < 4; ++r) dsum[st][r] = 0.f;

  for (int h = 0; h < 16; ++h){
    const size_t bh = (size_t)b * H_ + h;
    const short* qp = Qb + (bh * S_ + q0 + lr) * D_ + g * 8;
    bf16x8 qf0 = *(const bf16x8*)(qp);
    bf16x8 qf1 = *(const bf16x8*)(qp + 32);
    const short* kp = Kb + (bh * S_ + ks + lr) * D_ + g * 8;
    #pragma unroll 4
    for (int st = 0; st < 8; ++st){
      bf16x8 kf0 = *(const bf16x8*)(kp + (size_t)(st*16) * D_);
      bf16x8 kf1 = *(const bf16x8*)(kp + (size_t)(st*16) * D_ + 32);
      f32x4 s = (f32x4){0.f,0.f,0.f,0.f};
      s = __builtin_amdgcn_mfma_f32_16x16x32_bf16(qf0, kf0, s, 0, 0, 0);
      s = __builtin_amdgcn_mfma_f32_16x16x32_bf16(qf1, kf1, s, 0, 0, 0);
      #pragma unroll
      for (int r = 0; r < 4; ++r) dsum[st][r] += __expf(s[r] * 0.125f);
    }
  }

  // epilogue: masked? -1 : 1/sum  (coalesced: 16 contiguous k x 4 q-rows)
  #pragma unroll
  for (int st = 0; st < 8; ++st){
    #pragma unroll
    for (int r = 0; r < 4; ++r){
      const size_t qrow = (size_t)b * S_ + q0 + 4*g + r;
      const int kk = ks + st*16 + lr;
      int m = mask[qrow * S_ + kk];
      Z[qrow * S_ + kk] = m ? (1.0f / dsum[st][r]) : -1.0f;
    }
  }
}

// ---------- pass 2: p = z<0 ? 1/16 : exp(s/8)*z ; store p ; out = P V ----------
// 512 blocks x 512 thr (8 waves); wave = (b,h,q16). NO barriers: waves
// free-run; P transposed via wave-private swizzled LDS (lgkmcnt only).
// h in low grid bits -> per-XCD K+V L2-resident.
__global__ __launch_bounds__(512, 4) void pass2(const short* __restrict__ Qb,
                                                const short* __restrict__ Kb,
                                                const short* __restrict__ Vt,
                                                const float* __restrict__ Z,
                                                float* __restrict__ out,
                                                float* __restrict__ pout){
  __shared__ short pl[8][16][64];   // 16 KB: [wave][q][k-swizzled]

  const int tid = threadIdx.x, w = tid >> 6, lane = tid & 63;
  const int g = lane >> 4, lr = lane & 15;
  const int bid = blockIdx.x;
  const int strip = bid >> 5, b = (bid >> 4) & 1, h = bid & 15;
  const int q0 = strip * 128 + w * 16;
  const size_t bh = (size_t)b * 16 + h;

  // Q fragment (pre-cast bf16)
  bf16x8 qf0, qf1;
  {
    const short* qp = Qb + (bh * S_ + q0 + lr) * D_ + g * 8;
    qf0 = *(const bf16x8*)(qp);
    qf1 = *(const bf16x8*)(qp + 32);
  }

  f32x4 o[4];
  #pragma unroll
  for (int j = 0; j < 4; ++j) o[j] = (f32x4){0.f,0.f,0.f,0.f};

  const short* kb = Kb + (bh * S_ + lr) * D_ + g * 8;
  const short* vb = Vt + (bh * D_ + lr) * S_ + g * 8;
  const float* zl = Z    + ((size_t)b * S_ + q0 + 4*g) * S_ + lr;
  float*       pp = pout + (bh * S_ + q0 + 4*g) * S_ + lr;
  short*       plw = &pl[w][0][0];
  const int wl = wfun(lr);                 // read-side swizzle (row q = lr)

  for (int it = 0; it < 32; ++it){
    const int k0 = it * 64;

    // z loads (independent; issue early)
    f32x4 zv[4];
    #pragma unroll
    for (int t = 0; t < 4; ++t)
      #pragma unroll
      for (int r = 0; r < 4; ++r)
        zv[t][r] = zl[(size_t)r * S_ + k0 + 16*t];

    // QK^T
    f32x4 s[4];
    #pragma unroll
    for (int t = 0; t < 4; ++t){
      s[t] = (f32x4){0.f,0.f,0.f,0.f};
      bf16x8 kh0 = *(const bf16x8*)(kb + (size_t)(k0 + 16*t) * D_);
      bf16x8 kh1 = *(const bf16x8*)(kb + (size_t)(k0 + 16*t) * D_ + 32);
      s[t] = __builtin_amdgcn_mfma_f32_16x16x32_bf16(qf0, kh0, s[t], 0, 0, 0);
      s[t] = __builtin_amdgcn_mfma_f32_16x16x32_bf16(qf1, kh1, s[t], 0, 0, 0);
    }

    // V fragments (issued before p-stores so their wait skips the stores)
    bf16x8 vr[4][2];
    #pragma unroll
    for (int j = 0; j < 4; ++j)
      #pragma unroll
      for (int m = 0; m < 2; ++m)
        vr[j][m] = *(const bf16x8*)(vb + (size_t)(16*j) * S_ + k0 + 32*m);

    // e, p, global p-store, LDS transpose-write (swizzled)
    #pragma unroll
    for (int t = 0; t < 4; ++t){
      #pragma unroll
      for (int r = 0; r < 4; ++r){
        float e = __expf(s[t][r] * 0.125f);
        float z = zv[t][r];
        float p = (z < 0.f) ? 0.0625f : e * z;
        pp[(size_t)r * S_ + k0 + 16*t] = p;
        int q = 4*g + r;
        int ksw = (16*t + lr) ^ (8 * wfun(q));
        plw[q*64 + ksw] = f2bf(p);
      }
    }

    // wave-private transpose read (compiler inserts lgkmcnt; no s_barrier)
    bf16x8 pa0 = *(const bf16x8*)(plw + lr*64 + 8*( g      ^ wl));
    bf16x8 pa1 = *(const bf16x8*)(plw + lr*64 + 8*((4 + g) ^ wl));

    #pragma unroll
    for (int j = 0; j < 4; ++j){
      o[j] = __builtin_amdgcn_mfma_f32_16x16x32_bf16(pa0, vr[j][0], o[j], 0, 0, 0);
      o[j] = __builtin_amdgcn_mfma_f32_16x16x32_bf16(pa1, vr[j][1], o[j], 0, 0, 0);
    }
  }

  // epilogue
  #pragma unroll
  for (int j = 0; j < 4; ++j)
    #pragma unroll
    for (int r = 0; r < 4; ++r)
      out[(bh * S_ + q0 + 4*g + r) * D_ + 16*j + lr] = o[j][r];
}

extern "C" void kernel_launch(void* const* d_in, const int* in_sizes, int n_in,
                              void* d_out, int out_size, void* d_ws, size_t ws_size,
                              hipStream_t stream){
  const float* Q    = (const float*)d_in[0];
  const float* K    = (const float*)d_in[1];
  const float* V    = (const float*)d_in[2];
  const int*   mask = (const int*)d_in[3];

  const size_t nkv = (size_t)B_ * H_ * S_ * D_;   // 4,194,304

  short* Qb  = (short*)d_ws;                       // 8.4 MB
  short* Kb  = Qb + nkv;                           // 8.4 MB
  short* Vt  = Kb + nkv;                           // 8.4 MB
  float* Zb  = (float*)(Vt + nkv);                 // 33.5 MB (B*S*S fp32)

  float* out  = (float*)d_out;        // [B,H,S,D]
  float* pout = out + nkv;            // [B,H,S,S]

  cast_bf16  <<<(int)(nkv / (256 * 8)), 256, 0, stream>>>(Q, Qb);
  cast_bf16  <<<(int)(nkv / (256 * 8)), 256, 0, stream>>>(K, Kb);
  transpose_v<<<B_ * H_ * (S_ / 64),    256, 0, stream>>>(V, Vt);
  pass1      <<<1024,                   256, 0, stream>>>(Qb, Kb, mask, Zb);
  pass2      <<<512,                    512, 0, stream>>>(Qb, Kb, Vt, Zb, out, pout);
}